// Round 2
// baseline (742.337 us; speedup 1.0000x reference)
//
#include <hip/hip_runtime.h>
#include <float.h>

#define NV 4096
#define OSTRIDE 451
#define TILE 2048

// One KNN stage, executed by a 256-thread block that owns VB vertices,
// P = 256/VB threads per vertex, each scanning M/P points (chunk = 4096 for
// all stages). Points streamed through LDS as float4(x,y,z,-).
//
// Selection distance uses the DIRECT form (p-v).(p-v): abs err ~ulp(d2)
// (~1e-9), ~500x more accurate than the reference's ||x||^2+||y||^2-2x.y
// cancellation form (~5e-7). This matches the true / f64-arbiter ordering
// essentially always, strictly dominating the JAX-f32 expected's agreement.
template<int VB, int P, int M, int DF, int COFF>
__device__ __forceinline__ void stage_body(
    const float* __restrict__ verts,
    const float* __restrict__ pc,    // [3*M]
    const float* __restrict__ feat,  // [DF*M]
    float* __restrict__ out,
    int vbase,
    float4* __restrict__ s_tile,     // [TILE]
    float2* __restrict__ s_merge,    // [256*9] padded stride
    int*    __restrict__ s_idx,      // [VB*8]
    float*  __restrict__ s_w)        // [VB*8]
{
    const int tid = threadIdx.x;
    const int v = tid & (VB - 1);
    const int c = tid / VB;
    const int n = vbase + v;
    const float vx = verts[n*3+0], vy = verts[n*3+1], vz = verts[n*3+2];

    float dd[8];
    int   ii[8];
#pragma unroll
    for (int q = 0; q < 8; ++q) { dd[q] = FLT_MAX; ii[q] = 0; }

    constexpr int SLICE = TILE / P;

    for (int tb = 0; tb < M; tb += TILE) {
        __syncthreads();  // protect tile from previous scan
#pragma unroll
        for (int i = 0; i < TILE/256; ++i) {
            int j = tid + i*256;
            int m = tb + j;
            s_tile[j] = make_float4(pc[m], pc[M+m], pc[2*M+m], 0.0f);
        }
        __syncthreads();

        const int base = c * SLICE;
        const int mb = tb + base;
#pragma unroll 4
        for (int j = 0; j < SLICE; ++j) {
            float4 p = s_tile[base + j];
            float dx = __fsub_rn(p.x, vx);
            float dy = __fsub_rn(p.y, vy);
            float dz = __fsub_rn(p.z, vz);
            float d2 = __fmaf_rn(dz, dz, __fmaf_rn(dy, dy, __fmul_rn(dx, dx)));
            if (d2 < dd[7]) {       // strict <: stable, keeps earlier index on ties
                int mm = mb + j;
                bool b[7];
#pragma unroll
                for (int q = 0; q < 7; ++q) b[q] = d2 < dd[q];
#pragma unroll
                for (int q = 7; q >= 1; --q) {
                    bool hi = (q == 7) ? true : b[q];
                    dd[q] = b[q-1] ? dd[q-1] : (hi ? d2 : dd[q]);
                    ii[q] = b[q-1] ? ii[q-1] : (hi ? mm : ii[q]);
                }
                dd[0] = b[0] ? d2 : dd[0];
                ii[0] = b[0] ? mm : ii[0];
            }
        }
    }

    // publish partial top-8 lists (padded stride 9 to avoid bank conflicts)
#pragma unroll
    for (int q = 0; q < 8; ++q)
        s_merge[tid*9 + q] = make_float2(dd[q], __int_as_float(ii[q]));
    __syncthreads();

    if (tid < VB) {   // c == 0 thread merges the other P-1 partials (lexicographic)
        for (int cc = 1; cc < P; ++cc) {
            for (int s = 0; s < 8; ++s) {
                float2 pr = s_merge[(cc*VB + v)*9 + s];
                float cd = pr.x; int cm = __float_as_int(pr.y);
                bool less7 = (cd < dd[7]) || (cd == dd[7] && cm < ii[7]);
                if (!less7) break;   // partials sorted ascending -> safe
                bool b[7];
#pragma unroll
                for (int q = 0; q < 7; ++q)
                    b[q] = (cd < dd[q]) || (cd == dd[q] && cm < ii[q]);
#pragma unroll
                for (int q = 7; q >= 1; --q) {
                    bool hi = (q == 7) ? true : b[q];
                    dd[q] = b[q-1] ? dd[q-1] : (hi ? cd : dd[q]);
                    ii[q] = b[q-1] ? ii[q-1] : (hi ? cm : ii[q]);
                }
                dd[0] = b[0] ? cd : dd[0];
                ii[0] = b[0] ? cm : ii[0];
            }
        }
        // weights: reference recomputes dist2 from vec = nbr - vert,
        // numpy op order: round products, sequential add, no fma.
#pragma unroll
        for (int k = 0; k < 8; ++k) {
            int m = ii[k];
            float px = pc[m], py = pc[M+m], pz = pc[2*M+m];
            float dx = __fsub_rn(px, vx), dy = __fsub_rn(py, vy), dz = __fsub_rn(pz, vz);
            float dist2 = __fadd_rn(__fadd_rn(__fmul_rn(dx,dx), __fmul_rn(dy,dy)),
                                    __fmul_rn(dz,dz));
            float w = __fdiv_rn(1.0f, __fadd_rn(1.0f, dist2));
            s_idx[v*8 + k] = m;
            s_w [v*8 + k] = w;
        }
    }
    __syncthreads();

    // feature accumulation: out[n, COFF+f] = 0.125 * sum_k w_k * feat[f*M+idx_k]
    constexpr int TOT = VB * DF;
    for (int flat = tid; flat < TOT; flat += 256) {
        int v2 = flat / DF;
        int f  = flat & (DF - 1);
        float e[8];
#pragma unroll
        for (int k = 0; k < 8; ++k)
            e[k] = __fmul_rn(s_w[v2*8 + k], feat[f*M + s_idx[v2*8 + k]]);
        float sm = __fadd_rn(__fadd_rn(__fadd_rn(e[0],e[1]), __fadd_rn(e[2],e[3])),
                             __fadd_rn(__fadd_rn(e[4],e[5]), __fadd_rn(e[6],e[7])));
        out[(vbase + v2)*OSTRIDE + COFF + f] = __fmul_rn(0.125f, sm);
    }
}

__global__ __launch_bounds__(256)
void gp_kernel(const float* __restrict__ verts,
               const float* __restrict__ pc1, const float* __restrict__ f1,
               const float* __restrict__ pc2, const float* __restrict__ f2,
               const float* __restrict__ pc3, const float* __restrict__ f3,
               float* __restrict__ out)
{
    __shared__ float4 s_tile[TILE];      // 32 KiB
    __shared__ float2 s_merge[256*9];    // 18 KiB
    __shared__ int    s_idx[128*8];      // 4 KiB
    __shared__ float  s_w [128*8];       // 4 KiB

    int b = blockIdx.x;
    if (b < 128) {
        stage_body<32, 8, 32768,  64,   3>(verts, pc1, f1, out, b*32,
                                           s_tile, s_merge, s_idx, s_w);
    } else if (b < 192) {
        stage_body<64, 4, 16384, 128,  67>(verts, pc2, f2, out, (b-128)*64,
                                           s_tile, s_merge, s_idx, s_w);
    } else if (b < 224) {
        stage_body<128, 2, 8192, 256, 195>(verts, pc3, f3, out, (b-192)*128,
                                           s_tile, s_merge, s_idx, s_w);
    } else {
        // copy inputs into out[:, 0:3]
        for (int i = threadIdx.x; i < NV*3; i += 256)
            out[(i/3)*OSTRIDE + (i % 3)] = verts[i];
    }
}

extern "C" void kernel_launch(void* const* d_in, const int* in_sizes, int n_in,
                              void* d_out, int out_size, void* d_ws, size_t ws_size,
                              hipStream_t stream) {
    const float* verts = (const float*)d_in[0];
    // d_in[1] = pc0_coords: unused (reference discards stage 0)
    const float* pc1 = (const float*)d_in[2];
    const float* f1  = (const float*)d_in[3];
    const float* pc2 = (const float*)d_in[4];
    const float* f2  = (const float*)d_in[5];
    const float* pc3 = (const float*)d_in[6];
    const float* f3  = (const float*)d_in[7];
    gp_kernel<<<225, 256, 0, stream>>>(verts, pc1, f1, pc2, f2, pc3, f3,
                                       (float*)d_out);
}

// Round 3
// 381.152 us; speedup vs baseline: 1.9476x; 1.9476x over previous
//
#include <hip/hip_runtime.h>
#include <float.h>

#define NV 4096
#define OSTRIDE 451
#define TILE 1024
#define NT 512

// Shared memory: the point tile (scan phase) is dead by merge time, so the
// merge scratch aliases it via a union. s_idx/s_w live separately.
struct SMem {
    union {
        float4 tile[TILE];                       // 16 KiB (scan)
        struct { float dd[NT*8]; int ii[NT*8]; } mg;  // 32 KiB (merge)
    } u;
    int   idx[32*8];
    float w  [32*8];
};

// One KNN stage. Block owns VB vertices, P = NT/VB threads per vertex, each
// scanning M/P points. Selection distance = direct form (p-v).(p-v): abs err
// ~ulp(d2) (~1e-9), ~500x tighter than the reference's cancellation form, so
// ordering matches the f64 arbiter (8th/9th gap ~1e-3 >> 1e-9).
template<int VB, int P, int M, int DF, int COFF>
__device__ __forceinline__ void stage_body(
    const float* __restrict__ verts,
    const float* __restrict__ pc,    // [3*M]
    const float* __restrict__ feat,  // [DF*M]
    float* __restrict__ out,
    int vbase, SMem& sm)
{
    const int tid = threadIdx.x;
    const int v = tid & (VB - 1);
    const int c = tid / VB;
    const int n = vbase + v;
    const float vx = verts[n*3+0], vy = verts[n*3+1], vz = verts[n*3+2];

    float dd[8];
    int   ii[8];
#pragma unroll
    for (int q = 0; q < 8; ++q) { dd[q] = FLT_MAX; ii[q] = 0; }

    constexpr int SLICE = TILE / P;

    for (int tb = 0; tb < M; tb += TILE) {
        __syncthreads();  // protect tile from previous scan
#pragma unroll
        for (int i = 0; i < TILE/NT; ++i) {
            int j = tid + i*NT;
            int m = tb + j;
            sm.u.tile[j] = make_float4(pc[m], pc[M+m], pc[2*M+m], 0.0f);
        }
        __syncthreads();

        const int base = c * SLICE;
        const int mb = tb + base;
#pragma unroll 4
        for (int j = 0; j < SLICE; ++j) {
            float4 p = sm.u.tile[base + j];
            float dx = __fsub_rn(p.x, vx);
            float dy = __fsub_rn(p.y, vy);
            float dz = __fsub_rn(p.z, vz);
            float d2 = __fmaf_rn(dz, dz, __fmaf_rn(dy, dy, __fmul_rn(dx, dx)));
            if (d2 < dd[7]) {       // strict <: stable, keeps earlier index on ties
                int mm = mb + j;
                bool b[7];
#pragma unroll
                for (int q = 0; q < 7; ++q) b[q] = d2 < dd[q];
#pragma unroll
                for (int q = 7; q >= 1; --q) {
                    bool hi = (q == 7) ? true : b[q];
                    dd[q] = b[q-1] ? dd[q-1] : (hi ? d2 : dd[q]);
                    ii[q] = b[q-1] ? ii[q-1] : (hi ? mm : ii[q]);
                }
                dd[0] = b[0] ? d2 : dd[0];
                ii[0] = b[0] ? mm : ii[0];
            }
        }
    }
    __syncthreads();   // tile dead; mg aliases it

    // publish partial top-8 lists
#pragma unroll
    for (int q = 0; q < 8; ++q) {
        sm.u.mg.dd[tid*8 + q] = dd[q];
        sm.u.mg.ii[tid*8 + q] = ii[q];
    }
    __syncthreads();

    if (tid < VB) {   // c==0 thread merges the other P-1 partials (lexicographic)
        for (int cc = 1; cc < P; ++cc) {
            const int pb = (cc*VB + v)*8;
            for (int s = 0; s < 8; ++s) {
                float cd = sm.u.mg.dd[pb + s];
                int   cm = sm.u.mg.ii[pb + s];
                bool less7 = (cd < dd[7]) || (cd == dd[7] && cm < ii[7]);
                if (!less7) break;   // partials sorted ascending -> safe
                bool b[7];
#pragma unroll
                for (int q = 0; q < 7; ++q)
                    b[q] = (cd < dd[q]) || (cd == dd[q] && cm < ii[q]);
#pragma unroll
                for (int q = 7; q >= 1; --q) {
                    bool hi = (q == 7) ? true : b[q];
                    dd[q] = b[q-1] ? dd[q-1] : (hi ? cd : dd[q]);
                    ii[q] = b[q-1] ? ii[q-1] : (hi ? cm : ii[q]);
                }
                dd[0] = b[0] ? cd : dd[0];
                ii[0] = b[0] ? cm : ii[0];
            }
        }
        // weights: reference recomputes dist2 from vec = nbr - vert,
        // numpy op order: round products, sequential add, no fma.
#pragma unroll
        for (int k = 0; k < 8; ++k) {
            int m = ii[k];
            float px = pc[m], py = pc[M+m], pz = pc[2*M+m];
            float dx = __fsub_rn(px, vx), dy = __fsub_rn(py, vy), dz = __fsub_rn(pz, vz);
            float dist2 = __fadd_rn(__fadd_rn(__fmul_rn(dx,dx), __fmul_rn(dy,dy)),
                                    __fmul_rn(dz,dz));
            float w = __fdiv_rn(1.0f, __fadd_rn(1.0f, dist2));
            sm.idx[v*8 + k] = m;
            sm.w  [v*8 + k] = w;
        }
    }
    __syncthreads();

    // feature accumulation: out[n, COFF+f] = 0.125 * sum_k w_k * feat[f*M+idx_k]
    constexpr int TOT = VB * DF;
    for (int flat = tid; flat < TOT; flat += NT) {
        int v2 = flat / DF;
        int f  = flat & (DF - 1);
        float e[8];
#pragma unroll
        for (int k = 0; k < 8; ++k)
            e[k] = __fmul_rn(sm.w[v2*8 + k], feat[f*M + sm.idx[v2*8 + k]]);
        float smv = __fadd_rn(__fadd_rn(__fadd_rn(e[0],e[1]), __fadd_rn(e[2],e[3])),
                              __fadd_rn(__fadd_rn(e[4],e[5]), __fadd_rn(e[6],e[7])));
        out[(vbase + v2)*OSTRIDE + COFF + f] = __fmul_rn(0.125f, smv);
    }
}

__global__ __launch_bounds__(NT, 5)
void gp_kernel(const float* __restrict__ verts,
               const float* __restrict__ pc1, const float* __restrict__ f1,
               const float* __restrict__ pc2, const float* __restrict__ f2,
               const float* __restrict__ pc3, const float* __restrict__ f3,
               float* __restrict__ out)
{
    __shared__ SMem sm;
    int b = blockIdx.x;
    if (b < 256) {
        stage_body<16, 32, 32768,  64,   3>(verts, pc1, f1, out, b*16, sm);
    } else if (b < 512) {
        stage_body<16, 32, 16384, 128,  67>(verts, pc2, f2, out, (b-256)*16, sm);
    } else if (b < 640) {
        stage_body<32, 16,  8192, 256, 195>(verts, pc3, f3, out, (b-512)*32, sm);
    } else {
        // copy inputs into out[:, 0:3]
        for (int i = threadIdx.x; i < NV*3; i += NT)
            out[(i/3)*OSTRIDE + (i % 3)] = verts[i];
    }
}

extern "C" void kernel_launch(void* const* d_in, const int* in_sizes, int n_in,
                              void* d_out, int out_size, void* d_ws, size_t ws_size,
                              hipStream_t stream) {
    const float* verts = (const float*)d_in[0];
    // d_in[1] = pc0_coords: unused (reference discards stage 0)
    const float* pc1 = (const float*)d_in[2];
    const float* f1  = (const float*)d_in[3];
    const float* pc2 = (const float*)d_in[4];
    const float* f2  = (const float*)d_in[5];
    const float* pc3 = (const float*)d_in[6];
    const float* f3  = (const float*)d_in[7];
    gp_kernel<<<641, NT, 0, stream>>>(verts, pc1, f1, pc2, f2, pc3, f3,
                                      (float*)d_out);
}